// Round 3
// baseline (203.597 us; speedup 1.0000x reference)
//
#include <hip/hip_runtime.h>

// Problem constants (from reference): H=8, D=128 -> 1024 floats per (token,allheads) row
// PAGE=16 slots per page; cache layout [npages][2][PAGE][H][D] fp32.
#define PAGE_SZ 16
#define ROW_F4 256               // (H*D)/4 float4 per row
#define PAGE_F4 8192             // 2*PAGE_SZ*ROW_F4 float4 per page
#define ELEMS_PER_PAGE 32768     // floats per page

typedef float f32x4 __attribute__((ext_vector_type(4)));

// map[p] = (-1, _)        : page untouched by append
//          ( 1, t_base)   : page fully covered; slot s sources token t_base+s
//          ( 2, (b<<20)|j): page partially covered; recompute per-slot
__global__ void init_map_kernel(int2* __restrict__ map, int npages) {
    int i = blockIdx.x * blockDim.x + threadIdx.x;
    if (i < npages) map[i] = make_int2(-1, 0);
}

__global__ void fill_map_kernel(const int* __restrict__ append_indptr,
                                const int* __restrict__ page_indices,
                                const int* __restrict__ page_indptr,
                                const int* __restrict__ lastlen,
                                int2* __restrict__ map,
                                int B, int max_entries) {
    int idx = blockIdx.x * blockDim.x + threadIdx.x;
    if (idx >= max_entries) return;
    if (idx >= page_indptr[B]) return;        // beyond used page entries
    int b = 0;
    while (page_indptr[b + 1] <= idx) b++;
    int j         = idx - page_indptr[b];
    int num_pages = page_indptr[b + 1] - page_indptr[b];
    int num_new   = append_indptr[b + 1] - append_indptr[b];
    int seq_len   = (num_pages - 1) * PAGE_SZ + lastlen[b];
    int start     = seq_len - num_new;        // first appended logical position
    int pos0      = j * PAGE_SZ;
    int lo = pos0 > start ? pos0 : start;
    int hi = (pos0 + PAGE_SZ) < seq_len ? (pos0 + PAGE_SZ) : seq_len;
    if (lo >= hi) return;                     // no new tokens land in this page
    int p = page_indices[idx];
    if (pos0 >= start && pos0 + PAGE_SZ <= seq_len) {
        map[p] = make_int2(1, append_indptr[b] + pos0 - start);   // full page
    } else {
        map[p] = make_int2(2, (b << 20) | j);                     // partial page
    }
}

// One block per PAGE: 256 threads x 32 rows x float4 = 32 KiB, fully coalesced.
// Map lookup once per block; per-iteration loads are independent -> deep MLP.
__global__ void __launch_bounds__(256)
gather_page_kernel(const f32x4* __restrict__ k,
                   const f32x4* __restrict__ v,
                   const f32x4* __restrict__ cache_in,
                   const int* __restrict__ append_indptr,
                   const int* __restrict__ page_indptr,
                   const int* __restrict__ lastlen,
                   const int2* __restrict__ map,
                   f32x4* __restrict__ out) {
    const int page = blockIdx.x;
    const int tid  = threadIdx.x;             // float4 index within a row
    const long base = (long)page * PAGE_F4;

    int2 m = map[page];

    if (m.x == 1) {
        // Fully appended page: 16 consecutive tokens starting at m.y.
        const long tb = (long)m.y * ROW_F4;
        #pragma unroll
        for (int i = 0; i < PAGE_SZ; ++i) {
            f32x4 val = __builtin_nontemporal_load(&k[tb + (long)i * ROW_F4 + tid]);
            __builtin_nontemporal_store(val, &out[base + (long)i * ROW_F4 + tid]);
        }
        #pragma unroll
        for (int i = 0; i < PAGE_SZ; ++i) {
            f32x4 val = __builtin_nontemporal_load(&v[tb + (long)i * ROW_F4 + tid]);
            __builtin_nontemporal_store(val, &out[base + (long)(PAGE_SZ + i) * ROW_F4 + tid]);
        }
    } else if (m.x < 0) {
        // Untouched page: straight copy from input cache.
        #pragma unroll
        for (int i = 0; i < 2 * PAGE_SZ; ++i) {
            f32x4 val = __builtin_nontemporal_load(&cache_in[base + (long)i * ROW_F4 + tid]);
            __builtin_nontemporal_store(val, &out[base + (long)i * ROW_F4 + tid]);
        }
    } else {
        // Partially covered page: per-slot decision (rare path).
        int b = m.y >> 20, j = m.y & 0xFFFFF;
        int num_pages = page_indptr[b + 1] - page_indptr[b];
        int num_new   = append_indptr[b + 1] - append_indptr[b];
        int seq_len   = (num_pages - 1) * PAGE_SZ + lastlen[b];
        int start     = seq_len - num_new;
        #pragma unroll
        for (int i = 0; i < 2 * PAGE_SZ; ++i) {
            int kvsel = i >> 4;               // 0 = K rows, 1 = V rows
            int slot  = i & 15;
            int pos   = j * PAGE_SZ + slot;
            long e4   = base + (long)i * ROW_F4 + tid;
            f32x4 val;
            if (pos >= start && pos < seq_len) {
                long t = (long)(append_indptr[b] + pos - start);
                const f32x4* src = kvsel ? v : k;
                val = __builtin_nontemporal_load(&src[t * ROW_F4 + tid]);
            } else {
                val = __builtin_nontemporal_load(&cache_in[e4]);
            }
            __builtin_nontemporal_store(val, &out[e4]);
        }
    }
}

extern "C" void kernel_launch(void* const* d_in, const int* in_sizes, int n_in,
                              void* d_out, int out_size, void* d_ws, size_t ws_size,
                              hipStream_t stream) {
    const f32x4* k        = (const f32x4*)d_in[0];
    const f32x4* v        = (const f32x4*)d_in[1];
    const f32x4* cache_in = (const f32x4*)d_in[2];
    const int* append_indptr = (const int*)d_in[3];
    const int* page_indices  = (const int*)d_in[4];
    const int* page_indptr   = (const int*)d_in[5];
    const int* lastlen       = (const int*)d_in[6];
    // d_in[7] is page_size (=16), hard-coded as PAGE_SZ per reference constants.

    int B           = in_sizes[3] - 1;         // 8
    int max_entries = in_sizes[4];             // 2048
    int npages      = (int)((long)out_size / ELEMS_PER_PAGE);  // 4096

    int2* map = (int2*)d_ws;                   // npages * 8 bytes = 32 KiB

    init_map_kernel<<<(npages + 255) / 256, 256, 0, stream>>>(map, npages);
    fill_map_kernel<<<(max_entries + 255) / 256, 256, 0, stream>>>(
        append_indptr, page_indices, page_indptr, lastlen, map, B, max_entries);
    gather_page_kernel<<<npages, 256, 0, stream>>>(
        k, v, cache_in, append_indptr, page_indptr, lastlen, map,
        (f32x4*)d_out);
}